// Round 3
// baseline (1173.824 us; speedup 1.0000x reference)
//
#include <hip/hip_runtime.h>
#include <hip/hip_bf16.h>

#define T_STEPS 32
#define BATCH 256
#define EDIM 512
#define HDIM 512
#define G4 2048       // 4*H
#define VOCAB 3000
#define VPAD 3072
#define NBLK_LSTM 128

typedef short bf16x8 __attribute__((ext_vector_type(8)));
typedef float f32x4 __attribute__((ext_vector_type(4)));
typedef unsigned short u16x4 __attribute__((ext_vector_type(4)));

__device__ __forceinline__ unsigned short f2b(float f){
  union { float f; unsigned int u; } x; x.f = f;
  unsigned int u = x.u;
  unsigned int r = (u + 0x7fffu + ((u >> 16) & 1u)) >> 16;
  return (unsigned short)r;
}
__device__ __forceinline__ float sigm(float x){ return 1.0f / (1.0f + expf(-x)); }

__device__ __forceinline__ void gload_lds16(const unsigned short* g, unsigned short* l){
  __builtin_amdgcn_global_load_lds(
      (const __attribute__((address_space(1))) unsigned int*)g,
      (__attribute__((address_space(3))) unsigned int*)l, 16, 0, 0);
}

// ---------------- small prep kernels ----------------

__global__ void k_cvt(const float* __restrict__ in, unsigned short* __restrict__ out, int n){
  int i = blockIdx.x * blockDim.x + threadIdx.x;
  if (i < n) out[i] = f2b(in[i]);
}

__global__ void k_cvt_wout(const float* __restrict__ in, unsigned short* __restrict__ out){
  int i = blockIdx.x * blockDim.x + threadIdx.x; // over VPAD*1024
  if (i >= VPAD * 1024) return;
  int r = i >> 10, c = i & 1023;
  float v = (r < VOCAB) ? in[r * 1024 + c] : 0.0f;
  out[i] = f2b(v);
}

__global__ void k_build_xs(const float* __restrict__ img, const float* __restrict__ txt,
                           const float* __restrict__ emb, const int* __restrict__ ans,
                           unsigned short* __restrict__ xs){
  int i = blockIdx.x * blockDim.x + threadIdx.x; // over T*B*E
  if (i >= T_STEPS * BATCH * EDIM) return;
  int e = i & (EDIM - 1);
  int r = i >> 9;              // t*B + b
  int t = r >> 8, b = r & 255;
  float v;
  if (t == 0) v = (e < 256) ? img[b * 256 + e] : txt[b * 256 + (e - 256)];
  else { int tok = ans[b * T_STEPS + (t - 1)]; v = emb[(size_t)tok * EDIM + e]; }
  xs[i] = f2b(v);
}

__global__ void k_init_carry(const float* __restrict__ h0, unsigned short* __restrict__ hx){
  int i = blockIdx.x * blockDim.x + threadIdx.x;
  if (i < BATCH * HDIM) hx[i] = f2b(h0[i]);
}

// batch_sizes, packed row offsets, total rows, dest->src row map, barrier reset
__global__ void k_lens(const int* __restrict__ lengths, int* __restrict__ bs,
                       int* __restrict__ roff, int* __restrict__ meta,
                       int* __restrict__ rmap, unsigned* __restrict__ barrier){
  __shared__ int s[T_STEPS];
  __shared__ int sroff[T_STEPS + 1];
  int t = threadIdx.x; // 64 threads
  if (t < 2) barrier[t] = 0u;
  if (t < T_STEPS){
    int c = 0;
    for (int i = 0; i < BATCH; i++) c += (lengths[i] > t) ? 1 : 0;
    s[t] = c; bs[t] = c;
  }
  __syncthreads();
  if (t == 0){
    int acc = 0;
    for (int u = 0; u < T_STEPS; u++){ sroff[u] = acc; roff[u] = acc; acc += s[u]; }
    sroff[T_STEPS] = acc;
    meta[0] = acc;
  }
  __syncthreads();
  int ntot = sroff[T_STEPS];
  for (int r = t; r < T_STEPS * BATCH; r += 64){
    int tt = r >> 8, b = r & 255;
    if (b < s[tt]) rmap[sroff[tt] + b] = r;
  }
  for (int r = ntot + t; r < T_STEPS * BATCH; r += 64) rmap[r] = -1;
}

// gather hs||cs rows into packed dense A [8192][1024], zero tail rows
__global__ void k_pack(const unsigned short* __restrict__ hs, const unsigned short* __restrict__ cs,
                       const int* __restrict__ rmap, unsigned short* __restrict__ Ap){
  int i = blockIdx.x * 256 + threadIdx.x;   // over 8192*128 (8 elems/thread)
  int r = i >> 7, c = (i & 127) * 8;
  int src = rmap[r];
  bf16x8 v = {};
  if (src >= 0){
    v = (c < 512) ? *(const bf16x8*)(hs + (size_t)src * 512 + c)
                  : *(const bf16x8*)(cs + (size_t)src * 512 + (c - 512));
  }
  *(bf16x8*)(Ap + (size_t)r * 1024 + c) = v;
}

// ---------------- staged 128x128 GEMM core, BK=64, XOR-swizzled LDS ----------------
// A [*, K], B [*, K] bf16 K-contiguous. LDS rows are 128 B; slot s (16B) of LDS row r
// holds global slot s ^ (r&7)  (source pre-swizzled, global_load_lds dest linear).
template<int K>
__device__ __forceinline__ void gemm_tile(const unsigned short* __restrict__ A,
                                          const unsigned short* __restrict__ B,
                                          int row0, int col0,
                                          unsigned short* As, unsigned short* Bs,
                                          f32x4 acc[4][4]){
  const int tid = threadIdx.x, w = tid >> 6, l = tid & 63;
  const int la = l & 15, lkq = l >> 4;
  const int sr = l >> 3;            // row within 8-row staging group
  const int ss = (l & 7) ^ sr;      // pre-swizzled source slot
  const int wr = (w >> 1) * 64, wc = (w & 1) * 64;
  const unsigned short* gA = A + (size_t)(row0 + w * 32 + sr) * K + ss * 8;
  const unsigned short* gB = B + (size_t)(col0 + w * 32 + sr) * K + ss * 8;
  unsigned short* lA = As + (w * 32) * 64;
  unsigned short* lB = Bs + (w * 32) * 64;
  for (int k0 = 0; k0 < K; k0 += 64){
#pragma unroll
    for (int i = 0; i < 4; i++){
      gload_lds16(gA + (size_t)i * 8 * K + k0, lA + i * 8 * 64);
      gload_lds16(gB + (size_t)i * 8 * K + k0, lB + i * 8 * 64);
    }
    __syncthreads();
#pragma unroll
    for (int kk = 0; kk < 2; kk++){
      bf16x8 a[4], b[4];
#pragma unroll
      for (int i = 0; i < 4; i++){
        int r = wr + i * 16 + la;
        a[i] = *(const bf16x8*)(As + r * 64 + (((kk * 4 + lkq) ^ (r & 7)) << 3));
      }
#pragma unroll
      for (int i = 0; i < 4; i++){
        int r = wc + i * 16 + la;
        b[i] = *(const bf16x8*)(Bs + r * 64 + (((kk * 4 + lkq) ^ (r & 7)) << 3));
      }
#pragma unroll
      for (int mi = 0; mi < 4; mi++)
#pragma unroll
        for (int ni = 0; ni < 4; ni++)
          acc[mi][ni] = __builtin_amdgcn_mfma_f32_16x16x32_bf16(a[mi], b[ni], acc[mi][ni], 0, 0, 0);
    }
    __syncthreads();
  }
}

// ---------------- GEMM 1: XW = xs @ W_ih^T + b_ih + b_hh (fp32 out) ----------------
__global__ __launch_bounds__(256) void k_gemm_xw(const unsigned short* __restrict__ A,
                                                 const unsigned short* __restrict__ W,
                                                 const float* __restrict__ bih,
                                                 const float* __restrict__ bhh,
                                                 float* __restrict__ C){
  __shared__ unsigned short As[128 * 64], Bs[128 * 64];
  int row0 = blockIdx.x * 128, col0 = blockIdx.y * 128;
  f32x4 acc[4][4] = {};
  gemm_tile<EDIM>(A, W, row0, col0, As, Bs, acc);
  int tid = threadIdx.x, w = tid >> 6, l = tid & 63;
  int la = l & 15, r4 = (l >> 4) * 4;
  int wr = (w >> 1) * 64, wc = (w & 1) * 64;
#pragma unroll
  for (int ni = 0; ni < 4; ni++){
    int col = col0 + wc + ni * 16 + la;
    float bias = bih[col] + bhh[col];
#pragma unroll
    for (int mi = 0; mi < 4; mi++)
#pragma unroll
      for (int j = 0; j < 4; j++){
        int row = row0 + wr + mi * 16 + r4 + j;
        C[(size_t)row * G4 + col] = acc[mi][ni][j] + bias;
      }
  }
}

// ---------------- persistent LSTM recurrence (cooperative, 128 blocks) ----------------
__device__ __forceinline__ void gsync(unsigned* cnt, unsigned* gen, unsigned nb){
  __builtin_amdgcn_fence(__ATOMIC_RELEASE, "agent");
  __syncthreads();
  if (threadIdx.x == 0){
    unsigned e = __hip_atomic_load(gen, __ATOMIC_RELAXED, __HIP_MEMORY_SCOPE_AGENT);
    unsigned old = __hip_atomic_fetch_add(cnt, 1u, __ATOMIC_ACQ_REL, __HIP_MEMORY_SCOPE_AGENT);
    if (old == nb - 1u){
      __hip_atomic_store(cnt, 0u, __ATOMIC_RELAXED, __HIP_MEMORY_SCOPE_AGENT);
      __hip_atomic_fetch_add(gen, 1u, __ATOMIC_ACQ_REL, __HIP_MEMORY_SCOPE_AGENT);
    } else {
      while (__hip_atomic_load(gen, __ATOMIC_ACQUIRE, __HIP_MEMORY_SCOPE_AGENT) == e)
        __builtin_amdgcn_s_sleep(8);
    }
  }
  __syncthreads();
  __builtin_amdgcn_fence(__ATOMIC_ACQUIRE, "agent");
}

__global__ __launch_bounds__(256, 1) void k_lstm_persist(
    const float* __restrict__ XW, const unsigned short* __restrict__ Whh,
    unsigned short* __restrict__ hbA, unsigned short* __restrict__ hbB,
    const float* __restrict__ c0,
    unsigned short* __restrict__ hs, unsigned short* __restrict__ cs,
    unsigned* __restrict__ barrier){
  __shared__ unsigned char smem[32768];
  unsigned short* hA = (unsigned short*)smem;   // 32 rows x 512 bf16, swizzled
  float* gb = (float*)smem;                     // [4][32][36] f32, aliases hA post-MFMA
  unsigned* cnt = barrier;
  unsigned* gen = barrier + 1;
  const int tid = threadIdx.x, w = tid >> 6, l = tid & 63;
  const int la = l & 15, lkq = l >> 4;
  const int bid = blockIdx.x;
  const int row0 = (bid >> 4) * 32;   // 8 row groups
  const int h0c  = (bid & 15) * 32;   // 16 col groups
  // ---- Whh slice resident in registers: wave w = gate w, 32 cols, K=512 ----
  bf16x8 bw0[16], bw1[16];
  {
    const unsigned short* bp0 = Whh + (size_t)(w * 512 + h0c + la) * 512 + lkq * 8;
    const unsigned short* bp1 = Whh + (size_t)(w * 512 + h0c + 16 + la) * 512 + lkq * 8;
#pragma unroll
    for (int kk = 0; kk < 16; kk++){
      bw0[kk] = *(const bf16x8*)(bp0 + kk * 32);
      bw1[kk] = *(const bf16x8*)(bp1 + kk * 32);
    }
  }
  // ---- per-thread cell state: 4 cells (row rc, cols cc..cc+3) ----
  const int rc = tid >> 3, cc = (tid & 7) * 4;
  const size_t pcell = (size_t)(row0 + rc) * HDIM + h0c + cc;
  float cx4[4], hm1h[4], hm1c[4], hm2h[4], hm2c[4];
  {
    f32x4 c0v = *(const f32x4*)(c0 + pcell);
#pragma unroll
    for (int j = 0; j < 4; j++){ cx4[j] = c0v[j]; hm1h[j] = hm1c[j] = hm2h[j] = hm2c[j] = 0.0f; }
  }
  for (int t = 0; t < T_STEPS; t++){
    const unsigned short* hin = (t & 1) ? hbB : hbA;
    unsigned short* hout = (t & 1) ? hbA : hbB;
    const float* XWt = XW + (size_t)t * BATCH * G4;
    // prefetch this step's XW values (used after MFMA phase)
    f32x4 xw[4];
#pragma unroll
    for (int g2 = 0; g2 < 4; g2++)
      xw[g2] = *(const f32x4*)(XWt + (size_t)(row0 + rc) * G4 + g2 * 512 + h0c + cc);
    // stage h_in tile (32 rows x 512), swizzled source, linear LDS dest
#pragma unroll
    for (int i = 0; i < 8; i++){
      int r = w * 8 + i;
      gload_lds16(hin + (size_t)(row0 + r) * HDIM + ((l ^ (r & 7)) * 8), hA + r * 512);
    }
    __syncthreads();
    // MFMA: 2 M-tiles x 2 N-tiles x 16 K-steps, B from registers
    f32x4 acc00 = {}, acc01 = {}, acc10 = {}, acc11 = {};
#pragma unroll
    for (int kk = 0; kk < 16; kk++){
      int r0 = la, r1 = 16 + la;
      bf16x8 a0 = *(const bf16x8*)(hA + r0 * 512 + (((kk * 4 + lkq) ^ (r0 & 7)) << 3));
      bf16x8 a1 = *(const bf16x8*)(hA + r1 * 512 + (((kk * 4 + lkq) ^ (r1 & 7)) << 3));
      acc00 = __builtin_amdgcn_mfma_f32_16x16x32_bf16(a0, bw0[kk], acc00, 0, 0, 0);
      acc01 = __builtin_amdgcn_mfma_f32_16x16x32_bf16(a0, bw1[kk], acc01, 0, 0, 0);
      acc10 = __builtin_amdgcn_mfma_f32_16x16x32_bf16(a1, bw0[kk], acc10, 0, 0, 0);
      acc11 = __builtin_amdgcn_mfma_f32_16x16x32_bf16(a1, bw1[kk], acc11, 0, 0, 0);
    }
    __syncthreads();
    // exchange gates via LDS (wave w = gate w); gb row stride 36 (conflict-light)
    {
      int r4 = lkq * 4;
#pragma unroll
      for (int j = 0; j < 4; j++){
        gb[(w * 32 + 0 + r4 + j) * 36 + 0 + la]  = acc00[j];
        gb[(w * 32 + 0 + r4 + j) * 36 + 16 + la] = acc01[j];
        gb[(w * 32 + 16 + r4 + j) * 36 + 0 + la]  = acc10[j];
        gb[(w * 32 + 16 + r4 + j) * 36 + 16 + la] = acc11[j];
      }
    }
    __syncthreads();
    // cell update (4 cells per thread), history + cx in registers
    {
      const int do_res = (t >= 2 && (t % 3) == 0);
      u16x4 hsv, csv, hov;
#pragma unroll
      for (int j = 0; j < 4; j++){
        float gi = gb[(0 * 32 + rc) * 36 + cc + j] + xw[0][j];
        float gf = gb[(1 * 32 + rc) * 36 + cc + j] + xw[1][j];
        float gg = gb[(2 * 32 + rc) * 36 + cc + j] + xw[2][j];
        float go = gb[(3 * 32 + rc) * 36 + cc + j] + xw[3][j];
        float cy = sigm(gf) * cx4[j] + sigm(gi) * tanhf(gg);
        float hy = sigm(go) * tanhf(cy);
        hsv[j] = f2b(hy); csv[j] = f2b(cy);
        float hn = hy, cn = cy;
        if (do_res){ hn += hm2h[j]; cn += hm2c[j]; }
        hov[j] = f2b(hn);
        cx4[j] = cn;
        hm2h[j] = hm1h[j]; hm2c[j] = hm1c[j];
        hm1h[j] = hy; hm1c[j] = cy;
      }
      *(u16x4*)(hs + (size_t)t * BATCH * HDIM + pcell) = hsv;
      *(u16x4*)(cs + (size_t)t * BATCH * HDIM + pcell) = csv;
      *(u16x4*)(hout + pcell) = hov;
    }
    gsync(cnt, gen, (unsigned)NBLK_LSTM);
  }
}

// ---------------- GEMM 2: packed output projection (dense rows) ----------------
__global__ __launch_bounds__(256) void k_gemm_out(const unsigned short* __restrict__ Ap,
                                                  const unsigned short* __restrict__ Wo,
                                                  const float* __restrict__ bout,
                                                  const int* __restrict__ meta,
                                                  float* __restrict__ out){
  int ntot = meta[0];
  int row0 = blockIdx.x * 128, col0 = blockIdx.y * 128;
  if (row0 >= ntot) return;
  __shared__ unsigned short As[128 * 64], Bs[128 * 64];
  f32x4 acc[4][4] = {};
  gemm_tile<1024>(Ap, Wo, row0, col0, As, Bs, acc);
  int tid = threadIdx.x, w = tid >> 6, l = tid & 63;
  int la = l & 15, r4 = (l >> 4) * 4;
  int wr = (w >> 1) * 64, wc = (w & 1) * 64;
#pragma unroll
  for (int ni = 0; ni < 4; ni++){
    int col = col0 + wc + ni * 16 + la;
    if (col >= VOCAB) continue;
    float bias = bout[col];
#pragma unroll
    for (int mi = 0; mi < 4; mi++)
#pragma unroll
      for (int j = 0; j < 4; j++){
        int row = row0 + wr + mi * 16 + r4 + j;
        if (row < ntot) out[(size_t)row * VOCAB + col] = acc[mi][ni][j] + bias;
      }
  }
}

extern "C" void kernel_launch(void* const* d_in, const int* in_sizes, int n_in,
                              void* d_out, int out_size, void* d_ws, size_t ws_size,
                              hipStream_t stream){
  const float* img   = (const float*)d_in[0];
  const float* txt   = (const float*)d_in[1];
  const float* h0    = (const float*)d_in[2];
  const float* c0    = (const float*)d_in[3];
  const float* emb   = (const float*)d_in[4];
  const float* W_ih  = (const float*)d_in[5];
  const float* W_hh  = (const float*)d_in[6];
  const float* b_ih  = (const float*)d_in[7];
  const float* b_hh  = (const float*)d_in[8];
  const float* W_out = (const float*)d_in[9];
  const float* b_out = (const float*)d_in[10];
  const int* answer  = (const int*)d_in[11];
  const int* lengths = (const int*)d_in[12];
  float* out = (float*)d_out;

  char* ws = (char*)d_ws;
  size_t off = 0;
  auto alloc = [&](size_t bytes) -> void* {
    void* p = ws + off; off += (bytes + 255) & ~(size_t)255; return p;
  };
  unsigned short* Wih_b = (unsigned short*)alloc((size_t)G4 * EDIM * 2);
  unsigned short* Whh_b = (unsigned short*)alloc((size_t)G4 * HDIM * 2);
  unsigned short* Wo_b  = (unsigned short*)alloc((size_t)VPAD * 1024 * 2);
  unsigned short* xs    = (unsigned short*)alloc((size_t)T_STEPS * BATCH * EDIM * 2);
  float* XW             = (float*)alloc((size_t)T_STEPS * BATCH * G4 * 4);
  unsigned short* hs    = (unsigned short*)alloc((size_t)T_STEPS * BATCH * HDIM * 2);
  unsigned short* cs    = (unsigned short*)alloc((size_t)T_STEPS * BATCH * HDIM * 2);
  unsigned short* hxA   = (unsigned short*)alloc((size_t)BATCH * HDIM * 2);
  unsigned short* hxB   = (unsigned short*)alloc((size_t)BATCH * HDIM * 2);
  int* bsz  = (int*)alloc(T_STEPS * 4);
  int* roff = (int*)alloc(T_STEPS * 4);
  int* meta = (int*)alloc(256);
  int* rmap = (int*)alloc(T_STEPS * BATCH * 4);
  unsigned* barrier = (unsigned*)alloc(256);
  // Apack aliases XW: XW is dead after the persistent kernel; k_pack runs after it.
  unsigned short* Apack = (unsigned short*)XW; // 8192 x 1024 bf16 = 16 MB

  k_cvt<<<(G4 * EDIM + 255) / 256, 256, 0, stream>>>(W_ih, Wih_b, G4 * EDIM);
  k_cvt<<<(G4 * HDIM + 255) / 256, 256, 0, stream>>>(W_hh, Whh_b, G4 * HDIM);
  k_cvt_wout<<<(VPAD * 1024 + 255) / 256, 256, 0, stream>>>(W_out, Wo_b);
  k_build_xs<<<(T_STEPS * BATCH * EDIM + 255) / 256, 256, 0, stream>>>(img, txt, emb, answer, xs);
  k_init_carry<<<(BATCH * HDIM + 255) / 256, 256, 0, stream>>>(h0, hxA);
  k_lens<<<1, 64, 0, stream>>>(lengths, bsz, roff, meta, rmap, barrier);

  k_gemm_xw<<<dim3(T_STEPS * BATCH / 128, G4 / 128), 256, 0, stream>>>(xs, Wih_b, b_ih, b_hh, XW);

  {
    const float* XWp = XW; const unsigned short* Whhp = Whh_b;
    unsigned short* hA = hxA; unsigned short* hB = hxB;
    const float* c0p = c0; unsigned short* hsp = hs; unsigned short* csp = cs;
    unsigned* barp = barrier;
    void* args[] = { (void*)&XWp, (void*)&Whhp, (void*)&hA, (void*)&hB,
                     (void*)&c0p, (void*)&hsp, (void*)&csp, (void*)&barp };
    hipError_t e = hipLaunchCooperativeKernel((const void*)k_lstm_persist,
                                              dim3(NBLK_LSTM), dim3(256), args, 0, stream);
    if (e != hipSuccess){
      // 128 blocks x 256 thr @ 32KB LDS: 1/CU on 256 CUs — co-resident in practice
      k_lstm_persist<<<dim3(NBLK_LSTM), 256, 0, stream>>>(XW, Whh_b, hxA, hxB, c0, hs, cs, barrier);
    }
  }

  k_pack<<<T_STEPS * BATCH * 128 / 256, 256, 0, stream>>>(hs, cs, rmap, Apack);
  k_gemm_out<<<dim3(T_STEPS * BATCH / 128, VPAD / 128), 256, 0, stream>>>(Apack, Wo_b, b_out, meta, out);
}

// Round 4
// 416.318 us; speedup vs baseline: 2.8195x; 2.8195x over previous
//
#include <hip/hip_runtime.h>
#include <hip/hip_bf16.h>

#define T_STEPS 32
#define BATCH 256
#define EDIM 512
#define HDIM 512
#define G4 2048       // 4*H
#define VOCAB 3000
#define VPAD 3072

typedef short bf16x8 __attribute__((ext_vector_type(8)));
typedef float f32x4 __attribute__((ext_vector_type(4)));
typedef unsigned short u16x4 __attribute__((ext_vector_type(4)));

__device__ __forceinline__ unsigned short f2b(float f){
  union { float f; unsigned int u; } x; x.f = f;
  unsigned int u = x.u;
  unsigned int r = (u + 0x7fffu + ((u >> 16) & 1u)) >> 16;
  return (unsigned short)r;
}
__device__ __forceinline__ float b2f(unsigned short h){
  union { unsigned int u; float f; } x; x.u = ((unsigned int)h) << 16;
  return x.f;
}
__device__ __forceinline__ float sigm(float x){ return 1.0f / (1.0f + expf(-x)); }

__device__ __forceinline__ void gload_lds16(const unsigned short* g, unsigned short* l){
  __builtin_amdgcn_global_load_lds(
      (const __attribute__((address_space(1))) unsigned int*)g,
      (__attribute__((address_space(3))) unsigned int*)l, 16, 0, 0);
}

// ---------------- small prep kernels ----------------

__global__ void k_cvt(const float* __restrict__ in, unsigned short* __restrict__ out, int n){
  int i = blockIdx.x * blockDim.x + threadIdx.x;
  if (i < n) out[i] = f2b(in[i]);
}

__global__ void k_cvt_wout(const float* __restrict__ in, unsigned short* __restrict__ out){
  int i = blockIdx.x * blockDim.x + threadIdx.x; // over VPAD*1024
  if (i >= VPAD * 1024) return;
  int r = i >> 10, c = i & 1023;
  float v = (r < VOCAB) ? in[r * 1024 + c] : 0.0f;
  out[i] = f2b(v);
}

__global__ void k_build_xs(const float* __restrict__ img, const float* __restrict__ txt,
                           const float* __restrict__ emb, const int* __restrict__ ans,
                           unsigned short* __restrict__ xs){
  int i = blockIdx.x * blockDim.x + threadIdx.x; // over T*B*E
  if (i >= T_STEPS * BATCH * EDIM) return;
  int e = i & (EDIM - 1);
  int r = i >> 9;              // t*B + b
  int t = r >> 8, b = r & 255;
  float v;
  if (t == 0) v = (e < 256) ? img[b * 256 + e] : txt[b * 256 + (e - 256)];
  else { int tok = ans[b * T_STEPS + (t - 1)]; v = emb[(size_t)tok * EDIM + e]; }
  xs[i] = f2b(v);
}

__global__ void k_init_carry(const float* __restrict__ h0, const float* __restrict__ c0,
                             unsigned short* __restrict__ hx, float* __restrict__ cx){
  int i = blockIdx.x * blockDim.x + threadIdx.x;
  if (i < BATCH * HDIM){ hx[i] = f2b(h0[i]); cx[i] = c0[i]; }
}

// batch_sizes, packed row offsets, total rows, dest->src row map
__global__ void k_lens(const int* __restrict__ lengths, int* __restrict__ bs,
                       int* __restrict__ roff, int* __restrict__ meta,
                       int* __restrict__ rmap){
  __shared__ int s[T_STEPS];
  __shared__ int sroff[T_STEPS + 1];
  int t = threadIdx.x; // 64 threads
  if (t < T_STEPS){
    int c = 0;
    for (int i = 0; i < BATCH; i++) c += (lengths[i] > t) ? 1 : 0;
    s[t] = c; bs[t] = c;
  }
  __syncthreads();
  if (t == 0){
    int acc = 0;
    for (int u = 0; u < T_STEPS; u++){ sroff[u] = acc; roff[u] = acc; acc += s[u]; }
    sroff[T_STEPS] = acc;
    meta[0] = acc;
  }
  __syncthreads();
  int ntot = sroff[T_STEPS];
  for (int r = t; r < T_STEPS * BATCH; r += 64){
    int tt = r >> 8, b = r & 255;
    if (b < s[tt]) rmap[sroff[tt] + b] = r;
  }
  for (int r = ntot + t; r < T_STEPS * BATCH; r += 64) rmap[r] = -1;
}

// gather hs||cs rows into packed dense A [8192][1024], zero tail rows
__global__ void k_pack(const unsigned short* __restrict__ hs, const unsigned short* __restrict__ cs,
                       const int* __restrict__ rmap, unsigned short* __restrict__ Ap){
  int i = blockIdx.x * 256 + threadIdx.x;   // over 8192*128 (8 elems/thread)
  int r = i >> 7, c = (i & 127) * 8;
  int src = rmap[r];
  bf16x8 v = {};
  if (src >= 0){
    v = (c < 512) ? *(const bf16x8*)(hs + (size_t)src * 512 + c)
                  : *(const bf16x8*)(cs + (size_t)src * 512 + (c - 512));
  }
  *(bf16x8*)(Ap + (size_t)r * 1024 + c) = v;
}

// ---------------- staged 128x128 GEMM core, BK=64, XOR-swizzled LDS ----------------
template<int K>
__device__ __forceinline__ void gemm_tile(const unsigned short* __restrict__ A,
                                          const unsigned short* __restrict__ B,
                                          int row0, int col0,
                                          unsigned short* As, unsigned short* Bs,
                                          f32x4 acc[4][4]){
  const int tid = threadIdx.x, w = tid >> 6, l = tid & 63;
  const int la = l & 15, lkq = l >> 4;
  const int sr = l >> 3;            // row within 8-row staging group
  const int ss = (l & 7) ^ sr;      // pre-swizzled source slot
  const int wr = (w >> 1) * 64, wc = (w & 1) * 64;
  const unsigned short* gA = A + (size_t)(row0 + w * 32 + sr) * K + ss * 8;
  const unsigned short* gB = B + (size_t)(col0 + w * 32 + sr) * K + ss * 8;
  unsigned short* lA = As + (w * 32) * 64;
  unsigned short* lB = Bs + (w * 32) * 64;
  for (int k0 = 0; k0 < K; k0 += 64){
#pragma unroll
    for (int i = 0; i < 4; i++){
      gload_lds16(gA + (size_t)i * 8 * K + k0, lA + i * 8 * 64);
      gload_lds16(gB + (size_t)i * 8 * K + k0, lB + i * 8 * 64);
    }
    __syncthreads();
#pragma unroll
    for (int kk = 0; kk < 2; kk++){
      bf16x8 a[4], b[4];
#pragma unroll
      for (int i = 0; i < 4; i++){
        int r = wr + i * 16 + la;
        a[i] = *(const bf16x8*)(As + r * 64 + (((kk * 4 + lkq) ^ (r & 7)) << 3));
      }
#pragma unroll
      for (int i = 0; i < 4; i++){
        int r = wc + i * 16 + la;
        b[i] = *(const bf16x8*)(Bs + r * 64 + (((kk * 4 + lkq) ^ (r & 7)) << 3));
      }
#pragma unroll
      for (int mi = 0; mi < 4; mi++)
#pragma unroll
        for (int ni = 0; ni < 4; ni++)
          acc[mi][ni] = __builtin_amdgcn_mfma_f32_16x16x32_bf16(a[mi], b[ni], acc[mi][ni], 0, 0, 0);
    }
    __syncthreads();
  }
}

// ---------------- GEMM 1: XW = xs @ W_ih^T + b_ih + b_hh (bf16 out) ----------------
__global__ __launch_bounds__(256) void k_gemm_xw(const unsigned short* __restrict__ A,
                                                 const unsigned short* __restrict__ W,
                                                 const float* __restrict__ bih,
                                                 const float* __restrict__ bhh,
                                                 unsigned short* __restrict__ C){
  __shared__ unsigned short As[128 * 64], Bs[128 * 64];
  int row0 = blockIdx.x * 128, col0 = blockIdx.y * 128;
  f32x4 acc[4][4] = {};
  gemm_tile<EDIM>(A, W, row0, col0, As, Bs, acc);
  int tid = threadIdx.x, w = tid >> 6, l = tid & 63;
  int la = l & 15, r4 = (l >> 4) * 4;
  int wr = (w >> 1) * 64, wc = (w & 1) * 64;
#pragma unroll
  for (int ni = 0; ni < 4; ni++){
    int col = col0 + wc + ni * 16 + la;
    float bias = bih[col] + bhh[col];
#pragma unroll
    for (int mi = 0; mi < 4; mi++)
#pragma unroll
      for (int j = 0; j < 4; j++){
        int row = row0 + wr + mi * 16 + r4 + j;
        C[(size_t)row * G4 + col] = f2b(acc[mi][ni][j] + bias);
      }
  }
}

// ---------------- fused recurrent step: 256 blocks (16 rows x 32 hcols), wave=gate ----
__global__ __launch_bounds__(256) void k_lstm_step(const unsigned short* __restrict__ XWt,
                                                   const unsigned short* __restrict__ Whh,
                                                   const unsigned short* __restrict__ hin,
                                                   unsigned short* __restrict__ hout,
                                                   float* __restrict__ cxio,
                                                   unsigned short* __restrict__ hs_t,
                                                   unsigned short* __restrict__ cs_t,
                                                   const unsigned short* __restrict__ hs_m2,
                                                   const unsigned short* __restrict__ cs_m2,
                                                   int do_res){
  __shared__ float gbuf[4][16][33];
  const int w = threadIdx.x >> 6, l = threadIdx.x & 63;
  const int la = l & 15, lk = (l >> 4) * 8;
  const int row0 = blockIdx.x * 16;    // 16 row groups
  const int hc0  = blockIdx.y * 32;    // 16 col groups
  const int r4 = (l >> 4) * 4;
  // hoist XW loads (consumed after MFMA loop)
  float x0[4], x1[4];
#pragma unroll
  for (int j = 0; j < 4; j++){
    const unsigned short* xp = XWt + (size_t)(row0 + r4 + j) * G4 + w * 512 + hc0;
    x0[j] = b2f(xp[la]);
    x1[j] = b2f(xp[16 + la]);
  }
  f32x4 acc0 = {}, acc1 = {};
  const unsigned short* Ap = hin + (size_t)(row0 + la) * HDIM + lk;
  const unsigned short* Bp = Whh + (size_t)(w * HDIM + hc0 + la) * HDIM + lk;
#pragma unroll
  for (int k0 = 0; k0 < HDIM; k0 += 32){
    bf16x8 a  = *(const bf16x8*)(Ap + k0);
    bf16x8 b0 = *(const bf16x8*)(Bp + k0);
    bf16x8 b1 = *(const bf16x8*)(Bp + (size_t)16 * HDIM + k0);
    acc0 = __builtin_amdgcn_mfma_f32_16x16x32_bf16(a, b0, acc0, 0, 0, 0);
    acc1 = __builtin_amdgcn_mfma_f32_16x16x32_bf16(a, b1, acc1, 0, 0, 0);
  }
#pragma unroll
  for (int j = 0; j < 4; j++){
    gbuf[w][r4 + j][la]      = acc0[j] + x0[j];
    gbuf[w][r4 + j][16 + la] = acc1[j] + x1[j];
  }
  __syncthreads();
#pragma unroll
  for (int q = 0; q < 2; q++){
    int idx = threadIdx.x + q * 256;
    int r = idx >> 5, c = idx & 31;
    size_t p = (size_t)(row0 + r) * HDIM + hc0 + c;
    float gi = gbuf[0][r][c], gf = gbuf[1][r][c], gg = gbuf[2][r][c], go = gbuf[3][r][c];
    float cprev = cxio[p];
    float cy = sigm(gf) * cprev + sigm(gi) * tanhf(gg);
    float hy = sigm(go) * tanhf(cy);
    hs_t[p] = f2b(hy);
    cs_t[p] = f2b(cy);
    float hn = hy, cn = cy;
    if (do_res){ hn += b2f(hs_m2[p]); cn += b2f(cs_m2[p]); }
    hout[p] = f2b(hn);
    cxio[p] = cn;
  }
}

// ---------------- GEMM 2: packed output projection (dense rows) ----------------
__global__ __launch_bounds__(256) void k_gemm_out(const unsigned short* __restrict__ Ap,
                                                  const unsigned short* __restrict__ Wo,
                                                  const float* __restrict__ bout,
                                                  const int* __restrict__ meta,
                                                  float* __restrict__ out){
  int ntot = meta[0];
  int row0 = blockIdx.x * 128, col0 = blockIdx.y * 128;
  if (row0 >= ntot) return;
  __shared__ unsigned short As[128 * 64], Bs[128 * 64];
  f32x4 acc[4][4] = {};
  gemm_tile<1024>(Ap, Wo, row0, col0, As, Bs, acc);
  int tid = threadIdx.x, w = tid >> 6, l = tid & 63;
  int la = l & 15, r4 = (l >> 4) * 4;
  int wr = (w >> 1) * 64, wc = (w & 1) * 64;
#pragma unroll
  for (int ni = 0; ni < 4; ni++){
    int col = col0 + wc + ni * 16 + la;
    if (col >= VOCAB) continue;
    float bias = bout[col];
#pragma unroll
    for (int mi = 0; mi < 4; mi++)
#pragma unroll
      for (int j = 0; j < 4; j++){
        int row = row0 + wr + mi * 16 + r4 + j;
        if (row < ntot) out[(size_t)row * VOCAB + col] = acc[mi][ni][j] + bias;
      }
  }
}

extern "C" void kernel_launch(void* const* d_in, const int* in_sizes, int n_in,
                              void* d_out, int out_size, void* d_ws, size_t ws_size,
                              hipStream_t stream){
  const float* img   = (const float*)d_in[0];
  const float* txt   = (const float*)d_in[1];
  const float* h0    = (const float*)d_in[2];
  const float* c0    = (const float*)d_in[3];
  const float* emb   = (const float*)d_in[4];
  const float* W_ih  = (const float*)d_in[5];
  const float* W_hh  = (const float*)d_in[6];
  const float* b_ih  = (const float*)d_in[7];
  const float* b_hh  = (const float*)d_in[8];
  const float* W_out = (const float*)d_in[9];
  const float* b_out = (const float*)d_in[10];
  const int* answer  = (const int*)d_in[11];
  const int* lengths = (const int*)d_in[12];
  float* out = (float*)d_out;

  char* ws = (char*)d_ws;
  size_t off = 0;
  auto alloc = [&](size_t bytes) -> void* {
    void* p = ws + off; off += (bytes + 255) & ~(size_t)255; return p;
  };
  unsigned short* Wih_b = (unsigned short*)alloc((size_t)G4 * EDIM * 2);
  unsigned short* Whh_b = (unsigned short*)alloc((size_t)G4 * HDIM * 2);
  unsigned short* Wo_b  = (unsigned short*)alloc((size_t)VPAD * 1024 * 2);
  unsigned short* xs    = (unsigned short*)alloc((size_t)T_STEPS * BATCH * EDIM * 2);
  unsigned short* XW    = (unsigned short*)alloc((size_t)T_STEPS * BATCH * G4 * 2);
  unsigned short* hs    = (unsigned short*)alloc((size_t)T_STEPS * BATCH * HDIM * 2);
  unsigned short* cs    = (unsigned short*)alloc((size_t)T_STEPS * BATCH * HDIM * 2);
  unsigned short* hxA   = (unsigned short*)alloc((size_t)BATCH * HDIM * 2);
  unsigned short* hxB   = (unsigned short*)alloc((size_t)BATCH * HDIM * 2);
  float* cx             = (float*)alloc((size_t)BATCH * HDIM * 4);
  int* bsz  = (int*)alloc(T_STEPS * 4);
  int* roff = (int*)alloc(T_STEPS * 4);
  int* meta = (int*)alloc(256);
  int* rmap = (int*)alloc(T_STEPS * BATCH * 4);
  // Apack aliases XW (16 MB needed <= 32 MB): XW dead after the chain; k_pack runs after.
  unsigned short* Apack = (unsigned short*)XW;

  k_cvt<<<(G4 * EDIM + 255) / 256, 256, 0, stream>>>(W_ih, Wih_b, G4 * EDIM);
  k_cvt<<<(G4 * HDIM + 255) / 256, 256, 0, stream>>>(W_hh, Whh_b, G4 * HDIM);
  k_cvt_wout<<<(VPAD * 1024 + 255) / 256, 256, 0, stream>>>(W_out, Wo_b);
  k_build_xs<<<(T_STEPS * BATCH * EDIM + 255) / 256, 256, 0, stream>>>(img, txt, emb, answer, xs);
  k_init_carry<<<(BATCH * HDIM + 255) / 256, 256, 0, stream>>>(h0, c0, hxA, cx);
  k_lens<<<1, 64, 0, stream>>>(lengths, bsz, roff, meta, rmap);

  k_gemm_xw<<<dim3(T_STEPS * BATCH / 128, G4 / 128), 256, 0, stream>>>(xs, Wih_b, b_ih, b_hh, XW);

  unsigned short* hbuf[2] = { hxA, hxB };
  for (int t = 0; t < T_STEPS; t++){
    int do_res = (t >= 2 && (t % 3) == 0) ? 1 : 0;
    int tm2 = (t >= 2) ? (t - 2) : 0;
    k_lstm_step<<<dim3(BATCH / 16, HDIM / 32), 256, 0, stream>>>(
        XW + (size_t)t * BATCH * G4, Whh_b, hbuf[t & 1], hbuf[(t + 1) & 1], cx,
        hs + (size_t)t * BATCH * HDIM, cs + (size_t)t * BATCH * HDIM,
        hs + (size_t)tm2 * BATCH * HDIM, cs + (size_t)tm2 * BATCH * HDIM, do_res);
  }

  k_pack<<<T_STEPS * BATCH * 128 / 256, 256, 0, stream>>>(hs, cs, rmap, Apack);
  k_gemm_out<<<dim3(T_STEPS * BATCH / 128, VPAD / 128), 256, 0, stream>>>(Apack, Wo_b, b_out, meta, out);
}

// Round 5
// 378.102 us; speedup vs baseline: 3.1045x; 1.1011x over previous
//
#include <hip/hip_runtime.h>
#include <hip/hip_bf16.h>

#define T_STEPS 32
#define BATCH 256
#define EDIM 512
#define HDIM 512
#define G4 2048       // 4*H
#define VOCAB 3000
#define VPAD 3072

typedef short bf16x8 __attribute__((ext_vector_type(8)));
typedef float f32x4 __attribute__((ext_vector_type(4)));

__device__ __forceinline__ unsigned short f2b(float f){
  union { float f; unsigned int u; } x; x.f = f;
  unsigned int u = x.u;
  unsigned int r = (u + 0x7fffu + ((u >> 16) & 1u)) >> 16;
  return (unsigned short)r;
}
__device__ __forceinline__ float b2f(unsigned short h){
  union { unsigned int u; float f; } x; x.u = ((unsigned int)h) << 16;
  return x.f;
}
__device__ __forceinline__ float sigm(float x){ return 1.0f / (1.0f + expf(-x)); }

__device__ __forceinline__ void gload_lds16(const unsigned short* g, unsigned short* l){
  __builtin_amdgcn_global_load_lds(
      (const __attribute__((address_space(1))) unsigned int*)g,
      (__attribute__((address_space(3))) unsigned int*)l, 16, 0, 0);
}

// ---------------- small prep kernels ----------------

__global__ void k_cvt(const float* __restrict__ in, unsigned short* __restrict__ out, int n){
  int i = blockIdx.x * blockDim.x + threadIdx.x;
  if (i < n) out[i] = f2b(in[i]);
}

__global__ void k_cvt_wout(const float* __restrict__ in, unsigned short* __restrict__ out){
  int i = blockIdx.x * blockDim.x + threadIdx.x; // over VPAD*1024
  if (i >= VPAD * 1024) return;
  int r = i >> 10, c = i & 1023;
  float v = (r < VOCAB) ? in[r * 1024 + c] : 0.0f;
  out[i] = f2b(v);
}

__global__ void k_build_xs(const float* __restrict__ img, const float* __restrict__ txt,
                           const float* __restrict__ emb, const int* __restrict__ ans,
                           unsigned short* __restrict__ xs){
  int i = blockIdx.x * blockDim.x + threadIdx.x; // over T*B*E
  if (i >= T_STEPS * BATCH * EDIM) return;
  int e = i & (EDIM - 1);
  int r = i >> 9;              // t*B + b
  int t = r >> 8, b = r & 255;
  float v;
  if (t == 0) v = (e < 256) ? img[b * 256 + e] : txt[b * 256 + (e - 256)];
  else { int tok = ans[b * T_STEPS + (t - 1)]; v = emb[(size_t)tok * EDIM + e]; }
  xs[i] = f2b(v);
}

__global__ void k_init_carry(const float* __restrict__ h0, const float* __restrict__ c0,
                             unsigned short* __restrict__ hx, float* __restrict__ cx){
  int i = blockIdx.x * blockDim.x + threadIdx.x;
  if (i < BATCH * HDIM){ hx[i] = f2b(h0[i]); cx[i] = c0[i]; }
}

// batch_sizes, packed row offsets, total rows, dest->src row map
__global__ void k_lens(const int* __restrict__ lengths, int* __restrict__ bs,
                       int* __restrict__ roff, int* __restrict__ meta,
                       int* __restrict__ rmap){
  __shared__ int s[T_STEPS];
  __shared__ int sroff[T_STEPS + 1];
  int t = threadIdx.x; // 64 threads
  if (t < T_STEPS){
    int c = 0;
    for (int i = 0; i < BATCH; i++) c += (lengths[i] > t) ? 1 : 0;
    s[t] = c; bs[t] = c;
  }
  __syncthreads();
  if (t == 0){
    int acc = 0;
    for (int u = 0; u < T_STEPS; u++){ sroff[u] = acc; roff[u] = acc; acc += s[u]; }
    sroff[T_STEPS] = acc;
    meta[0] = acc;
  }
  __syncthreads();
  int ntot = sroff[T_STEPS];
  for (int r = t; r < T_STEPS * BATCH; r += 64){
    int tt = r >> 8, b = r & 255;
    if (b < s[tt]) rmap[sroff[tt] + b] = r;
  }
  for (int r = ntot + t; r < T_STEPS * BATCH; r += 64) rmap[r] = -1;
}

// ---------------- staged 128x128 GEMM core, BK=64, XOR-swizzled LDS ----------------
template<int K>
__device__ __forceinline__ void gemm_tile(const unsigned short* __restrict__ A,
                                          const unsigned short* __restrict__ B,
                                          int row0, int col0,
                                          unsigned short* As, unsigned short* Bs,
                                          f32x4 acc[4][4]){
  const int tid = threadIdx.x, w = tid >> 6, l = tid & 63;
  const int la = l & 15, lkq = l >> 4;
  const int sr = l >> 3;            // row within 8-row staging group
  const int ss = (l & 7) ^ sr;      // pre-swizzled source slot
  const int wr = (w >> 1) * 64, wc = (w & 1) * 64;
  const unsigned short* gA = A + (size_t)(row0 + w * 32 + sr) * K + ss * 8;
  const unsigned short* gB = B + (size_t)(col0 + w * 32 + sr) * K + ss * 8;
  unsigned short* lA = As + (w * 32) * 64;
  unsigned short* lB = Bs + (w * 32) * 64;
  for (int k0 = 0; k0 < K; k0 += 64){
#pragma unroll
    for (int i = 0; i < 4; i++){
      gload_lds16(gA + (size_t)i * 8 * K + k0, lA + i * 8 * 64);
      gload_lds16(gB + (size_t)i * 8 * K + k0, lB + i * 8 * 64);
    }
    __syncthreads();
#pragma unroll
    for (int kk = 0; kk < 2; kk++){
      bf16x8 a[4], b[4];
#pragma unroll
      for (int i = 0; i < 4; i++){
        int r = wr + i * 16 + la;
        a[i] = *(const bf16x8*)(As + r * 64 + (((kk * 4 + lkq) ^ (r & 7)) << 3));
      }
#pragma unroll
      for (int i = 0; i < 4; i++){
        int r = wc + i * 16 + la;
        b[i] = *(const bf16x8*)(Bs + r * 64 + (((kk * 4 + lkq) ^ (r & 7)) << 3));
      }
#pragma unroll
      for (int mi = 0; mi < 4; mi++)
#pragma unroll
        for (int ni = 0; ni < 4; ni++)
          acc[mi][ni] = __builtin_amdgcn_mfma_f32_16x16x32_bf16(a[mi], b[ni], acc[mi][ni], 0, 0, 0);
    }
    __syncthreads();
  }
}

// ---------------- GEMM 1: XW = xs @ W_ih^T + b_ih + b_hh (bf16 out) ----------------
__global__ __launch_bounds__(256) void k_gemm_xw(const unsigned short* __restrict__ A,
                                                 const unsigned short* __restrict__ W,
                                                 const float* __restrict__ bih,
                                                 const float* __restrict__ bhh,
                                                 unsigned short* __restrict__ C){
  __shared__ unsigned short As[128 * 64], Bs[128 * 64];
  int row0 = blockIdx.x * 128, col0 = blockIdx.y * 128;
  f32x4 acc[4][4] = {};
  gemm_tile<EDIM>(A, W, row0, col0, As, Bs, acc);
  int tid = threadIdx.x, w = tid >> 6, l = tid & 63;
  int la = l & 15, r4 = (l >> 4) * 4;
  int wr = (w >> 1) * 64, wc = (w & 1) * 64;
#pragma unroll
  for (int ni = 0; ni < 4; ni++){
    int col = col0 + wc + ni * 16 + la;
    float bias = bih[col] + bhh[col];
#pragma unroll
    for (int mi = 0; mi < 4; mi++)
#pragma unroll
      for (int j = 0; j < 4; j++){
        int row = row0 + wr + mi * 16 + r4 + j;
        C[(size_t)row * G4 + col] = f2b(acc[mi][ni][j] + bias);
      }
  }
}

// ---------------- fused recurrent step: 512 blocks (16 rows x 16 hcols), wave=gate ----
__global__ __launch_bounds__(256) void k_lstm_step(const unsigned short* __restrict__ XWt,
                                                   const unsigned short* __restrict__ Whh,
                                                   const unsigned short* __restrict__ hin,
                                                   unsigned short* __restrict__ hout,
                                                   float* __restrict__ cxio,
                                                   unsigned short* __restrict__ hs_t,
                                                   unsigned short* __restrict__ cs_t,
                                                   const unsigned short* __restrict__ hs_m2,
                                                   const unsigned short* __restrict__ cs_m2,
                                                   int do_res){
  __shared__ unsigned short hA[16 * 512];   // swizzled h tile
  __shared__ float gbuf[4][16][17];
  const int w = threadIdx.x >> 6, l = threadIdx.x & 63;
  const int la = l & 15, lkq = l >> 4;
  const int row0 = blockIdx.x * 16;
  const int hc0  = blockIdx.y * 16;
  // stage h tile: wave w stages rows {w, 4+w, 8+w, 12+w}; source slot pre-swizzled,
  // LDS dest linear (one full 1KB row per instruction)
#pragma unroll
  for (int i = 0; i < 4; i++){
    int r = i * 4 + w;
    gload_lds16(hin + (size_t)(row0 + r) * HDIM + ((l ^ (r & 7)) << 3), hA + r * 512);
  }
  // hoist XW (consumed after MFMA loop)
  const int r4 = lkq * 4;
  float x[4];
#pragma unroll
  for (int j = 0; j < 4; j++)
    x[j] = b2f(XWt[(size_t)(row0 + r4 + j) * G4 + w * HDIM + hc0 + la]);
  const unsigned short* Bp = Whh + (size_t)(w * HDIM + hc0 + la) * HDIM + lkq * 8;
  __syncthreads();
  f32x4 acc = {};
#pragma unroll
  for (int kk = 0; kk < 16; kk++){
    bf16x8 a = *(const bf16x8*)(hA + la * 512 + (((kk * 4 + lkq) ^ (la & 7)) << 3));
    bf16x8 b = *(const bf16x8*)(Bp + kk * 32);
    acc = __builtin_amdgcn_mfma_f32_16x16x32_bf16(a, b, acc, 0, 0, 0);
  }
#pragma unroll
  for (int j = 0; j < 4; j++) gbuf[w][r4 + j][la] = acc[j] + x[j];
  __syncthreads();
  {
    int r = threadIdx.x >> 4, c = threadIdx.x & 15;
    size_t p = (size_t)(row0 + r) * HDIM + hc0 + c;
    float gi = gbuf[0][r][c], gf = gbuf[1][r][c], gg = gbuf[2][r][c], go = gbuf[3][r][c];
    float cprev = cxio[p];
    float cy = sigm(gf) * cprev + sigm(gi) * tanhf(gg);
    float hy = sigm(go) * tanhf(cy);
    hs_t[p] = f2b(hy);
    cs_t[p] = f2b(cy);
    float hn = hy, cn = cy;
    if (do_res){ hn += b2f(hs_m2[p]); cn += b2f(cs_m2[p]); }
    hout[p] = f2b(hn);
    cxio[p] = cn;
  }
}

// ---------------- GEMM 2: packed output projection, A gathered via rmap ----------------
__global__ __launch_bounds__(256) void k_gemm_out(const unsigned short* __restrict__ hs,
                                                  const unsigned short* __restrict__ cs,
                                                  const unsigned short* __restrict__ Wo,
                                                  const float* __restrict__ bout,
                                                  const int* __restrict__ meta,
                                                  const int* __restrict__ rmap,
                                                  float* __restrict__ out){
  int ntot = meta[0];
  int row0 = blockIdx.x * 128, col0 = blockIdx.y * 128;
  if (row0 >= ntot) return;
  __shared__ unsigned short As[128 * 64], Bs[128 * 64];
  const int tid = threadIdx.x, w = tid >> 6, l = tid & 63;
  const int la = l & 15, lkq = l >> 4;
  const int sr = l >> 3, ss = (l & 7) ^ sr;
  const int wr = (w >> 1) * 64, wc = (w & 1) * 64;
  // gather source rows once (reused across all K-steps); rmap<0 -> row 0 (masked at store)
  int srow[4];
#pragma unroll
  for (int i = 0; i < 4; i++){
    int rr = rmap[row0 + w * 32 + sr + i * 8];
    srow[i] = rr < 0 ? 0 : rr;
  }
  const unsigned short* gB = Wo + (size_t)(col0 + w * 32 + sr) * 1024 + ss * 8;
  unsigned short* lA = As + (w * 32) * 64;
  unsigned short* lB = Bs + (w * 32) * 64;
  f32x4 acc[4][4] = {};
  for (int k0 = 0; k0 < 1024; k0 += 64){
#pragma unroll
    for (int i = 0; i < 4; i++){
      const unsigned short* srcA = (k0 < 512)
          ? hs + (size_t)srow[i] * 512 + k0 + ss * 8
          : cs + (size_t)srow[i] * 512 + (k0 - 512) + ss * 8;
      gload_lds16(srcA, lA + i * 8 * 64);
      gload_lds16(gB + (size_t)i * 8 * 1024 + k0, lB + i * 8 * 64);
    }
    __syncthreads();
#pragma unroll
    for (int kk = 0; kk < 2; kk++){
      bf16x8 a[4], b[4];
#pragma unroll
      for (int i = 0; i < 4; i++){
        int r = wr + i * 16 + la;
        a[i] = *(const bf16x8*)(As + r * 64 + (((kk * 4 + lkq) ^ (r & 7)) << 3));
      }
#pragma unroll
      for (int i = 0; i < 4; i++){
        int r = wc + i * 16 + la;
        b[i] = *(const bf16x8*)(Bs + r * 64 + (((kk * 4 + lkq) ^ (r & 7)) << 3));
      }
#pragma unroll
      for (int mi = 0; mi < 4; mi++)
#pragma unroll
        for (int ni = 0; ni < 4; ni++)
          acc[mi][ni] = __builtin_amdgcn_mfma_f32_16x16x32_bf16(a[mi], b[ni], acc[mi][ni], 0, 0, 0);
    }
    __syncthreads();
  }
  int r4 = (l >> 4) * 4;
#pragma unroll
  for (int ni = 0; ni < 4; ni++){
    int col = col0 + wc + ni * 16 + la;
    if (col >= VOCAB) continue;
    float bias = bout[col];
#pragma unroll
    for (int mi = 0; mi < 4; mi++)
#pragma unroll
      for (int j = 0; j < 4; j++){
        int row = row0 + wr + mi * 16 + r4 + j;
        if (row < ntot) out[(size_t)row * VOCAB + col] = acc[mi][ni][j] + bias;
      }
  }
}

extern "C" void kernel_launch(void* const* d_in, const int* in_sizes, int n_in,
                              void* d_out, int out_size, void* d_ws, size_t ws_size,
                              hipStream_t stream){
  const float* img   = (const float*)d_in[0];
  const float* txt   = (const float*)d_in[1];
  const float* h0    = (const float*)d_in[2];
  const float* c0    = (const float*)d_in[3];
  const float* emb   = (const float*)d_in[4];
  const float* W_ih  = (const float*)d_in[5];
  const float* W_hh  = (const float*)d_in[6];
  const float* b_ih  = (const float*)d_in[7];
  const float* b_hh  = (const float*)d_in[8];
  const float* W_out = (const float*)d_in[9];
  const float* b_out = (const float*)d_in[10];
  const int* answer  = (const int*)d_in[11];
  const int* lengths = (const int*)d_in[12];
  float* out = (float*)d_out;

  char* ws = (char*)d_ws;
  size_t off = 0;
  auto alloc = [&](size_t bytes) -> void* {
    void* p = ws + off; off += (bytes + 255) & ~(size_t)255; return p;
  };
  unsigned short* Wih_b = (unsigned short*)alloc((size_t)G4 * EDIM * 2);
  unsigned short* Whh_b = (unsigned short*)alloc((size_t)G4 * HDIM * 2);
  unsigned short* Wo_b  = (unsigned short*)alloc((size_t)VPAD * 1024 * 2);
  unsigned short* xs    = (unsigned short*)alloc((size_t)T_STEPS * BATCH * EDIM * 2);
  unsigned short* XW    = (unsigned short*)alloc((size_t)T_STEPS * BATCH * G4 * 2);
  unsigned short* hs    = (unsigned short*)alloc((size_t)T_STEPS * BATCH * HDIM * 2);
  unsigned short* cs    = (unsigned short*)alloc((size_t)T_STEPS * BATCH * HDIM * 2);
  unsigned short* hxA   = (unsigned short*)alloc((size_t)BATCH * HDIM * 2);
  unsigned short* hxB   = (unsigned short*)alloc((size_t)BATCH * HDIM * 2);
  float* cx             = (float*)alloc((size_t)BATCH * HDIM * 4);
  int* bsz  = (int*)alloc(T_STEPS * 4);
  int* roff = (int*)alloc(T_STEPS * 4);
  int* meta = (int*)alloc(256);
  int* rmap = (int*)alloc(T_STEPS * BATCH * 4);

  k_cvt<<<(G4 * EDIM + 255) / 256, 256, 0, stream>>>(W_ih, Wih_b, G4 * EDIM);
  k_cvt<<<(G4 * HDIM + 255) / 256, 256, 0, stream>>>(W_hh, Whh_b, G4 * HDIM);
  k_cvt_wout<<<(VPAD * 1024 + 255) / 256, 256, 0, stream>>>(W_out, Wo_b);
  k_build_xs<<<(T_STEPS * BATCH * EDIM + 255) / 256, 256, 0, stream>>>(img, txt, emb, answer, xs);
  k_init_carry<<<(BATCH * HDIM + 255) / 256, 256, 0, stream>>>(h0, c0, hxA, cx);
  k_lens<<<1, 64, 0, stream>>>(lengths, bsz, roff, meta, rmap);

  k_gemm_xw<<<dim3(T_STEPS * BATCH / 128, G4 / 128), 256, 0, stream>>>(xs, Wih_b, b_ih, b_hh, XW);

  unsigned short* hbuf[2] = { hxA, hxB };
  for (int t = 0; t < T_STEPS; t++){
    int do_res = (t >= 2 && (t % 3) == 0) ? 1 : 0;
    int tm2 = (t >= 2) ? (t - 2) : 0;
    k_lstm_step<<<dim3(BATCH / 16, HDIM / 16), 256, 0, stream>>>(
        XW + (size_t)t * BATCH * G4, Whh_b, hbuf[t & 1], hbuf[(t + 1) & 1], cx,
        hs + (size_t)t * BATCH * HDIM, cs + (size_t)t * BATCH * HDIM,
        hs + (size_t)tm2 * BATCH * HDIM, cs + (size_t)tm2 * BATCH * HDIM, do_res);
  }

  k_gemm_out<<<dim3(T_STEPS * BATCH / 128, VPAD / 128), 256, 0, stream>>>(hs, cs, Wo_b, b_out, meta, rmap, out);
}